// Round 9
// baseline (1927.124 us; speedup 1.0000x reference)
//
#include <hip/hip_runtime.h>
#include <hip/hip_fp16.h>

#define NN 25000
#define EE 400000
#define FIN 128
#define FE 16
#define CH 32
#define SLOPE 0.01f
#define PROJ_BLOCKS 391   // ceil(25000/64)
#define AUX_BLOCKS 128               // 4 WtP blocks + 124 aggr-zero blocks
#define W16_SHORTS (1024 * 16)       // 32KB weight image, 16 shorts/row (bias separate)
#define EPT 128                      // edges per k_edge tile (EE % EPT == 0 -> no guards)
#define NT (EE / EPT)                // 3125 tiles
#define PBLK 768                     // persistent blocks = 3 per CU (53KB LDS), static stride

typedef __attribute__((ext_vector_type(8))) short bf16x8;
typedef __attribute__((ext_vector_type(4))) float f32x4;

__device__ __forceinline__ float lrelu(float v) { return fmaxf(v, SLOPE * v); }

__device__ __forceinline__ f32x4 lrelu4(f32x4 v) {
    f32x4 s = v * SLOPE;
#if __has_builtin(__builtin_elementwise_max)
    return __builtin_elementwise_max(v, s);   // v_pk_max_f32
#else
    f32x4 r;
    r[0] = fmaxf(v[0], s[0]); r[1] = fmaxf(v[1], s[1]);
    r[2] = fmaxf(v[2], s[2]); r[3] = fmaxf(v[3], s[3]);
    return r;
#endif
}

// float -> bf16 bits, round-to-nearest-even
__device__ __forceinline__ short f2bf(float f) {
    union { float f; unsigned u; } v; v.f = f;
    unsigned r = (v.u + 0x7fffu + ((v.u >> 16) & 1u)) >> 16;
    return (short)r;
}

__device__ __forceinline__ bf16x8 cvt8(const float4& a, const float4& b) {
    return (bf16x8){f2bf(a.x), f2bf(a.y), f2bf(a.z), f2bf(a.w),
                    f2bf(b.x), f2bf(b.y), f2bf(b.z), f2bf(b.w)};
}

// ---------------- Kernel 1: fused prep
// blocks [0, PROJ_BLOCKS): h = leaky(x @ W_in + b_in) via MFMA (64 nodes/block)
// blocks [PROJ, +4): WtP16[co][16] = bf16 W_edge^T row
// blocks [+4, +AUX): zero aggrH (f16, 1.6MB)
__global__ void __launch_bounds__(256)
k_pre(const float* __restrict__ x, const float* __restrict__ W_in,
      const float* __restrict__ b_in, const float* __restrict__ W_edge,
      const float* __restrict__ b_edge,
      float* __restrict__ h, __half* __restrict__ aggrH, short* __restrict__ WtP16) {
    __shared__ short Wt1[CH * 136];
    int tid = threadIdx.x;

    if (blockIdx.x >= PROJ_BLOCKS) {
        int ab = blockIdx.x - PROJ_BLOCKS;
        if (ab < 4) {
            int co = ab * 256 + tid;                       // 0..1023
            short row[16] __attribute__((aligned(16)));
#pragma unroll
            for (int k = 0; k < 16; k++) row[k] = f2bf(W_edge[k * 1024 + co]);
            uint4* dstp = (uint4*)(WtP16 + co * 16);       // co*32B, 16B-aligned
            dstp[0] = ((uint4*)row)[0]; dstp[1] = ((uint4*)row)[1];
        } else {
            int t = (ab - 4) * 256 + tid;
            uint4 z = make_uint4(0u, 0u, 0u, 0u);
            // NN*CH halfs = 1.6MB = 100000 uint4
            for (int i = t; i < NN * CH * 2 / 16; i += (AUX_BLOCKS - 4) * 256)
                ((uint4*)aggrH)[i] = z;
        }
        return;
    }

#pragma unroll
    for (int i = 0; i < 16; i++) {
        int id = tid + 256 * i;           // id = k*32 + c
        int k = id >> 5, c = id & 31;
        Wt1[c * 136 + k] = f2bf(W_in[id]);
    }
    __syncthreads();

    int wave = tid >> 6, lane = tid & 63;
    int n16 = lane & 15, quad = lane >> 4;
    int node0 = blockIdx.x * 64 + wave * 16;

    f32x4 D[2];
#pragma unroll
    for (int ch = 0; ch < 2; ch++) {
        float bb = b_in[ch * 16 + n16];
        D[ch] = (f32x4){bb, bb, bb, bb};
    }
    int arow = node0 + n16; if (arow >= NN) arow = NN - 1;
#pragma unroll
    for (int kb = 0; kb < 4; kb++) {
        const float4* xp = (const float4*)(x + (size_t)arow * FIN + kb * 32 + quad * 8);
        float4 xa = xp[0], xb = xp[1];
        bf16x8 A = cvt8(xa, xb);
#pragma unroll
        for (int ch = 0; ch < 2; ch++) {
            bf16x8 B = *(const bf16x8*)&Wt1[(ch * 16 + n16) * 136 + kb * 32 + quad * 8];
            D[ch] = __builtin_amdgcn_mfma_f32_16x16x32_bf16(A, B, D[ch], 0, 0, 0);
        }
    }
#pragma unroll
    for (int ch = 0; ch < 2; ch++)
#pragma unroll
        for (int r = 0; r < 4; r++) {
            int nn = node0 + quad * 4 + r;
            if (nn < NN) h[(size_t)nn * CH + ch * 16 + n16] = lrelu(D[ch][r]);
        }
}

// ---------------- Kernel 2: persistent edge kernel (R7 core, static stride) +
// PACKED-F16 SCATTER. R8 post-mortem: 4 structures (R0/R3/R7/R8) all floor at
// ~78-90us with every pipe <50% and occupancy-independent; the shared invariant
// is the atomic stream: 12.8M f32 lane-requests = WRITE_SIZE 50MB exactly, served
// at the memory-side coherence point at ~64 req/cyc chip-wide => ~83us wall.
// Fix: aggr in f16, scatter via global_atomic_pk_add_f16 (unsafeAtomicAdd(__half2*)):
// channel pair (2j,2j+1) sits in lanes n16=2j/2j+1 of the SAME quad (same edge row),
// one __shfl_xor(1) pairs them, even-n16 lanes issue => 6.4M requests, 25MB.
// Precision: |aggr|<~25, f16 ulp ~0.02, ~16-term accumulation error ~0.05-0.1 << 0.5 tol.
// Dynamic scheduling (R8) reverted: it cost 8us (refuted theory).
__global__ void __launch_bounds__(256, 2)
k_edge(const short* __restrict__ WtP16,  // [1024][16] bf16 image (plain layout)
       const float* __restrict__ ea,     // [EE][16] f32
       const int* __restrict__ src,
       const int* __restrict__ dst,
       const float* __restrict__ h,
       __half* __restrict__ aggrH,
       const float* __restrict__ b_edge) {
    __shared__ short W16[W16_SHORTS];        // 32768 B (slot-swizzled)
    __shared__ float biasF[1024];            //  4096 B (raw f32 b_edge)
    __shared__ float hsT[CH * EPT];          // 16384 B, hsT[c][e]

    int tid = threadIdx.x;

    // stage: 2048 uint4 W16 (swizzled) + 256 uint4 biasF = 9 iters/thread
#pragma unroll
    for (int j = 0; j < 9; j++) {
        int idx = tid + 256 * j;
        if (idx < 2048) {
            int co = idx >> 1, s = idx & 1;
            int p = (co << 1) | (s ^ ((co >> 2) & 1));     // slot-XOR
            ((uint4*)W16)[p] = ((const uint4*)WtP16)[idx];
        } else if (idx < 2304) {
            ((uint4*)biasF)[idx - 2048] = ((const uint4*)b_edge)[idx - 2048];
        }
    }

    const int lane = tid & 63;
    const int wave = tid >> 6;
    const int n16 = lane & 15, quad = lane >> 4;
    const int t0 = wave * 32, t1 = t0 + 16;
    const int eH = tid >> 1, halfH = tid & 1;      // gather role

    // B base: row co = cb*16+n16, phys slot = (q&1) ^ ((co>>2)&1); (co>>2)&1 == (n16>>2)&1
    const int qeff = (quad & 1) ^ ((n16 >> 2) & 1);
    const short* Bbase = W16 + n16 * 16 + qeff * 8;          // + cb*256 shorts (imm)
    const float* h0b = hsT + t0 + quad * 4;                  // + c*EPT (imm)
    const float* h1b = hsT + t1 + quad * 4;

    struct PrefT {
        float hv[16];
        float4 e0a, e0b, e1a, e1b;
        int d[8];
    };
    PrefT Pa, Pb;

    auto PREF = [&](int tile, PrefT& P) {
        int base = tile * EPT;
        int s = src[base + eH];
        const float4* hp = (const float4*)(h + (size_t)s * CH + halfH * 16);
        float4 v0 = hp[0], v1 = hp[1], v2 = hp[2], v3 = hp[3];
        *(float4*)&P.hv[0] = v0;  *(float4*)&P.hv[4] = v1;
        *(float4*)&P.hv[8] = v2;  *(float4*)&P.hv[12] = v3;
        if (quad < 2) {
            const float4* p0 = (const float4*)(ea + (size_t)(base + t0 + n16) * FE + quad * 8);
            P.e0a = p0[0]; P.e0b = p0[1];
            const float4* p1 = (const float4*)(ea + (size_t)(base + t1 + n16) * FE + quad * 8);
            P.e1a = p1[0]; P.e1b = p1[1];
        }
#pragma unroll
        for (int r = 0; r < 4; r++) {
            P.d[r]     = dst[base + t0 + quad * 4 + r];
            P.d[4 + r] = dst[base + t1 + quad * 4 + r];
        }
    };

    auto WRITE = [&](PrefT& P) {
        // addr = (halfH*16+j)*128 + eH -> bank eH%32, 2 lanes/bank = free
        float* hd = hsT + halfH * (16 * EPT) + eH;
#pragma unroll
        for (int j = 0; j < 16; j++) hd[j * EPT] = P.hv[j];
    };

    auto COMPUTE = [&](PrefT& P) {
        bf16x8 A0 = (bf16x8){0,0,0,0,0,0,0,0}, A1 = A0;    // quads 2,3: A==0 (k 16..31)
        if (quad < 2) { A0 = cvt8(P.e0a, P.e0b); A1 = cvt8(P.e1a, P.e1b); }

        f32x4 m0[2], m1[2];
        m0[0] = (f32x4){0,0,0,0}; m0[1] = m0[0]; m1[0] = m0[0]; m1[1] = m0[0];

#pragma unroll
        for (int c = 0; c < 32; c++) {
            f32x4 hc0 = *(const f32x4*)(h0b + c * EPT);    // quad-disjoint banks, free
            f32x4 hc1 = *(const f32x4*)(h1b + c * EPT);
            float b0 = biasF[32 * c + n16];                // quad-broadcast, bank-free
            float b1 = biasF[32 * c + 16 + n16];
            f32x4 Cb0 = (f32x4){b0, b0, b0, b0};
            f32x4 Cb1 = (f32x4){b1, b1, b1, b1};
            {
                bf16x8 B = *(const bf16x8*)(Bbase + (2 * c) * 256);
                f32x4 D0 = __builtin_amdgcn_mfma_f32_16x16x32_bf16(A0, B, Cb0, 0, 0, 0);
                f32x4 D1 = __builtin_amdgcn_mfma_f32_16x16x32_bf16(A1, B, Cb0, 0, 0, 0);
                m0[0] += lrelu4(D0) * hc0;
                m1[0] += lrelu4(D1) * hc1;
            }
            {
                bf16x8 B = *(const bf16x8*)(Bbase + (2 * c + 1) * 256);
                f32x4 D0 = __builtin_amdgcn_mfma_f32_16x16x32_bf16(A0, B, Cb1, 0, 0, 0);
                f32x4 D1 = __builtin_amdgcn_mfma_f32_16x16x32_bf16(A1, B, Cb1, 0, 0, 0);
                m0[1] += lrelu4(D0) * hc0;
                m1[1] += lrelu4(D1) * hc1;
            }
        }

        // ---- packed-f16 scatter: lane pair (n16=2j, 2j+1) of the same quad holds
        // channels (oh*16+2j, oh*16+2j+1) of the SAME edge row (row depends only on
        // quad,r). Even lane packs {own, partner} into __half2 and issues ONE
        // global_atomic_pk_add_f16 -> half the lane-requests, half the bytes.
        // Address (row*32 + oh*16 + n16)*2B, n16 even -> 4B-aligned.
#pragma unroll
        for (int r = 0; r < 4; r++) {
#pragma unroll
            for (int oh = 0; oh < 2; oh++) {
                float a0 = m0[oh][r], b0s = __shfl_xor(a0, 1, 64);
                float a1 = m1[oh][r], b1s = __shfl_xor(a1, 1, 64);
                if ((n16 & 1) == 0) {
                    __half2 v0 = __floats2half2_rn(a0, b0s);
                    unsafeAtomicAdd((__half2*)(aggrH + (size_t)P.d[r] * CH + oh * 16 + n16), v0);
                    __half2 v1 = __floats2half2_rn(a1, b1s);
                    unsafeAtomicAdd((__half2*)(aggrH + (size_t)P.d[4 + r] * CH + oh * 16 + n16), v1);
                }
            }
        }
    };

    // persistent loop, 2-phase unrolled (static Pa/Pb), STATIC tile stride.
    int T = blockIdx.x;
    PREF(T, Pa);
    while (true) {
        __syncthreads();
        WRITE(Pa);
        __syncthreads();
        int nt = T + PBLK;
        bool more = (nt < NT);
        if (more) PREF(nt, Pb);          // flies under COMPUTE
        COMPUTE(Pa);
        if (!more) break;
        T = nt;

        __syncthreads();
        WRITE(Pb);
        __syncthreads();
        nt = T + PBLK;
        more = (nt < NT);
        if (more) PREF(nt, Pa);
        COMPUTE(Pb);
        if (!more) break;
        T = nt;
    }
}

// ---------------- Kernel 3 (MFMA): out = leaky(aggr + h@W_root + b_conv) @ W_out + b_out
__global__ void __launch_bounds__(256)
k_node(const __half* __restrict__ aggrH,
       const float* __restrict__ h,
       const float* __restrict__ W_root,
       const float* __restrict__ b_conv,
       const float* __restrict__ W_out,
       const float* __restrict__ b_out,
       float* __restrict__ out) {
    __shared__ short WrB[CH * 40];   // W_root^T bf16: [o][c], stride 40 shorts (80B)
    __shared__ float WoS[CH];
    int tid = threadIdx.x;
    if (tid < 128) {
        int o = tid >> 2, c0 = (tid & 3) * 8;
        short tmp[8] __attribute__((aligned(16)));
#pragma unroll
        for (int j = 0; j < 8; j++) tmp[j] = f2bf(W_root[(c0 + j) * CH + o]);
        *(bf16x8*)&WrB[o * 40 + c0] = *(bf16x8*)tmp;
    } else if (tid < 160) {
        WoS[tid - 128] = W_out[tid - 128];
    }
    __syncthreads();

    int wave = tid >> 6, lane = tid & 63;
    int n16 = lane & 15, quad = lane >> 4;
    int node0 = blockIdx.x * 64 + wave * 16;

    int arow = node0 + n16; if (arow >= NN) arow = NN - 1;
    const float4* hp = (const float4*)(h + (size_t)arow * CH + quad * 8);
    float4 ha = hp[0], hb = hp[1];
    bf16x8 A = cvt8(ha, hb);
    float bc0 = b_conv[n16], bc1 = b_conv[16 + n16];
    f32x4 C0, C1;
#pragma unroll
    for (int r = 0; r < 4; r++) {
        int nr = node0 + quad * 4 + r; int cr = (nr < NN) ? nr : NN - 1;
        C0[r] = __half2float(aggrH[(size_t)cr * CH + n16]) + bc0;
        C1[r] = __half2float(aggrH[(size_t)cr * CH + 16 + n16]) + bc1;
    }
    bf16x8 B0 = *(const bf16x8*)&WrB[n16 * 40 + quad * 8];
    bf16x8 B1 = *(const bf16x8*)&WrB[(16 + n16) * 40 + quad * 8];
    f32x4 D0 = __builtin_amdgcn_mfma_f32_16x16x32_bf16(A, B0, C0, 0, 0, 0);
    f32x4 D1 = __builtin_amdgcn_mfma_f32_16x16x32_bf16(A, B1, C1, 0, 0, 0);

    float w0 = WoS[n16], w1 = WoS[16 + n16];
    f32x4 p;
#pragma unroll
    for (int r = 0; r < 4; r++)
        p[r] = lrelu(D0[r]) * w0 + lrelu(D1[r]) * w1;
#pragma unroll
    for (int mk = 1; mk < 16; mk <<= 1) {
#pragma unroll
        for (int r = 0; r < 4; r++) p[r] += __shfl_xor(p[r], mk, 64);
    }
    if (n16 == 0) {
        float bo = b_out[0];
#pragma unroll
        for (int r = 0; r < 4; r++) {
            int nr = node0 + quad * 4 + r;
            if (nr < NN) out[nr] = p[r] + bo;
        }
    }
}

extern "C" void kernel_launch(void* const* d_in, const int* in_sizes, int n_in,
                              void* d_out, int out_size, void* d_ws, size_t ws_size,
                              hipStream_t stream) {
    const float* x      = (const float*)d_in[0];
    const int*   ei     = (const int*)d_in[1];
    const float* ea     = (const float*)d_in[2];
    const float* W_in   = (const float*)d_in[3];
    const float* b_in   = (const float*)d_in[4];
    const float* W_edge = (const float*)d_in[5];
    const float* b_edge = (const float*)d_in[6];
    const float* W_root = (const float*)d_in[7];
    const float* b_conv = (const float*)d_in[8];
    const float* W_out  = (const float*)d_in[9];
    const float* b_out  = (const float*)d_in[10];
    float* out   = (float*)d_out;
    float* h     = (float*)d_ws;                      // [NN*CH] f32 (3.2MB)
    __half* aggrH = (__half*)(h + (size_t)NN * CH);   // [NN*CH] f16 (1.6MB)
    short* WtP16 = (short*)(aggrH + (size_t)NN * CH); // [1024*16] bf16 image

    k_pre<<<PROJ_BLOCKS + AUX_BLOCKS, 256, 0, stream>>>(x, W_in, b_in, W_edge, b_edge,
                                                        h, aggrH, WtP16);
    k_edge<<<PBLK, 256, 0, stream>>>(WtP16, ea, ei, ei + EE, h, aggrH, b_edge);
    k_node<<<PROJ_BLOCKS, 256, 0, stream>>>(aggrH, h, W_root, b_conv, W_out, b_out, out);
}

// Round 10
// 161.362 us; speedup vs baseline: 11.9429x; 11.9429x over previous
//
#include <hip/hip_runtime.h>
#include <hip/hip_fp16.h>

#define NN 25000
#define EE 400000
#define FIN 128
#define FE 16
#define CH 32
#define SLOPE 0.01f
#define PROJ_BLOCKS 391   // ceil(25000/64)
#define AUX_BLOCKS 128               // 4 WtP blocks + 124 aggr-zero blocks
#define W16_SHORTS (1024 * 16)       // 32KB weight image, 16 shorts/row (bias separate)
#define EPT 128                      // edges per k_edge tile (EE % EPT == 0 -> no guards)
#define NT (EE / EPT)                // 3125 tiles
#define PBLK 768                     // persistent blocks = 3 per CU (53KB LDS), static stride

typedef __attribute__((ext_vector_type(8))) short bf16x8;
typedef __attribute__((ext_vector_type(4))) float f32x4;

__device__ __forceinline__ float lrelu(float v) { return fmaxf(v, SLOPE * v); }

__device__ __forceinline__ f32x4 lrelu4(f32x4 v) {
    f32x4 s = v * SLOPE;
#if __has_builtin(__builtin_elementwise_max)
    return __builtin_elementwise_max(v, s);   // v_pk_max_f32
#else
    f32x4 r;
    r[0] = fmaxf(v[0], s[0]); r[1] = fmaxf(v[1], s[1]);
    r[2] = fmaxf(v[2], s[2]); r[3] = fmaxf(v[3], s[3]);
    return r;
#endif
}

// float -> bf16 bits, round-to-nearest-even
__device__ __forceinline__ short f2bf(float f) {
    union { float f; unsigned u; } v; v.f = f;
    unsigned r = (v.u + 0x7fffu + ((v.u >> 16) & 1u)) >> 16;
    return (short)r;
}

__device__ __forceinline__ bf16x8 cvt8(const float4& a, const float4& b) {
    return (bf16x8){f2bf(a.x), f2bf(a.y), f2bf(a.z), f2bf(a.w),
                    f2bf(b.x), f2bf(b.y), f2bf(b.z), f2bf(b.w)};
}

// ---------------- Kernel 1: fused prep
// blocks [0, PROJ_BLOCKS): h = leaky(x @ W_in + b_in) via MFMA (64 nodes/block)
// blocks [PROJ, +4): WtP16[co][16] = bf16 W_edge^T row
// blocks [+4, +AUX): zero aggrP (f16 permuted-channel image, 1.6MB)
__global__ void __launch_bounds__(256)
k_pre(const float* __restrict__ x, const float* __restrict__ W_in,
      const float* __restrict__ b_in, const float* __restrict__ W_edge,
      const float* __restrict__ b_edge,
      float* __restrict__ h, __half* __restrict__ aggrP, short* __restrict__ WtP16) {
    __shared__ short Wt1[CH * 136];
    int tid = threadIdx.x;

    if (blockIdx.x >= PROJ_BLOCKS) {
        int ab = blockIdx.x - PROJ_BLOCKS;
        if (ab < 4) {
            int co = ab * 256 + tid;                       // 0..1023
            short row[16] __attribute__((aligned(16)));
#pragma unroll
            for (int k = 0; k < 16; k++) row[k] = f2bf(W_edge[k * 1024 + co]);
            uint4* dstp = (uint4*)(WtP16 + co * 16);       // co*32B, 16B-aligned
            dstp[0] = ((uint4*)row)[0]; dstp[1] = ((uint4*)row)[1];
        } else {
            int t = (ab - 4) * 256 + tid;
            uint4 z = make_uint4(0u, 0u, 0u, 0u);
            // NN*CH halfs = 1.6MB = 100000 uint4
            for (int i = t; i < NN * CH * 2 / 16; i += (AUX_BLOCKS - 4) * 256)
                ((uint4*)aggrP)[i] = z;
        }
        return;
    }

#pragma unroll
    for (int i = 0; i < 16; i++) {
        int id = tid + 256 * i;           // id = k*32 + c
        int k = id >> 5, c = id & 31;
        Wt1[c * 136 + k] = f2bf(W_in[id]);
    }
    __syncthreads();

    int wave = tid >> 6, lane = tid & 63;
    int n16 = lane & 15, quad = lane >> 4;
    int node0 = blockIdx.x * 64 + wave * 16;

    f32x4 D[2];
#pragma unroll
    for (int ch = 0; ch < 2; ch++) {
        float bb = b_in[ch * 16 + n16];
        D[ch] = (f32x4){bb, bb, bb, bb};
    }
    int arow = node0 + n16; if (arow >= NN) arow = NN - 1;
#pragma unroll
    for (int kb = 0; kb < 4; kb++) {
        const float4* xp = (const float4*)(x + (size_t)arow * FIN + kb * 32 + quad * 8);
        float4 xa = xp[0], xb = xp[1];
        bf16x8 A = cvt8(xa, xb);
#pragma unroll
        for (int ch = 0; ch < 2; ch++) {
            bf16x8 B = *(const bf16x8*)&Wt1[(ch * 16 + n16) * 136 + kb * 32 + quad * 8];
            D[ch] = __builtin_amdgcn_mfma_f32_16x16x32_bf16(A, B, D[ch], 0, 0, 0);
        }
    }
#pragma unroll
    for (int ch = 0; ch < 2; ch++)
#pragma unroll
        for (int r = 0; r < 4; r++) {
            int nn = node0 + quad * 4 + r;
            if (nn < NN) h[(size_t)nn * CH + ch * 16 + n16] = lrelu(D[ch][r]);
        }
}

// ---------------- Kernel 2: persistent edge kernel (R7 core, UNCHANGED body) +
// LEAN PACKED-F16 SCATTER. R9 post-mortem: the shuffle-based pairing spilled
// (VGPR 76->128-at-cap, FETCH/WRITE ~2.2GB each) and never tested the atomic-wall
// theory. Lean retry: lane n16 ALREADY holds a channel pair of the same dst row
// (ch n16 at oh=0, ch 16+n16 at oh=1), so store aggr PERMUTED as
// aggrP[node][n16][oh] -> the pair is adjacent in memory. One v_cvt_pkrtz +
// one unsafeAtomicAdd(__half2) per (row, r): 16 atomics -> 8, zero shuffles,
// zero divergence, register shape identical to R7's proven 76-VGPR body.
// Atomic requests 12.8M -> 6.4M; bytes 50MB -> 25MB. Tests R8's request-rate
// wall (12.8M / ~66 per cyc ~ 83us) cleanly.
// Numerics: |aggr| <~ 25, f16 ulp ~0.02, ~16-term sums -> err ~0.05 << 0.5 tol
// (R9 passed correctness with f16 aggr).
__global__ void __launch_bounds__(256, 2)
k_edge(const short* __restrict__ WtP16,  // [1024][16] bf16 image (plain layout)
       const float* __restrict__ ea,     // [EE][16] f32
       const int* __restrict__ src,
       const int* __restrict__ dst,
       const float* __restrict__ h,
       __half* __restrict__ aggrP,       // [NN][16][2] permuted-channel f16
       const float* __restrict__ b_edge) {
    __shared__ short W16[W16_SHORTS];        // 32768 B (slot-swizzled)
    __shared__ float biasF[1024];            //  4096 B (raw f32 b_edge)
    __shared__ float hsT[CH * EPT];          // 16384 B, hsT[c][e]

    int tid = threadIdx.x;

    // stage: 2048 uint4 W16 (swizzled) + 256 uint4 biasF = 9 iters/thread
#pragma unroll
    for (int j = 0; j < 9; j++) {
        int idx = tid + 256 * j;
        if (idx < 2048) {
            int co = idx >> 1, s = idx & 1;
            int p = (co << 1) | (s ^ ((co >> 2) & 1));     // slot-XOR
            ((uint4*)W16)[p] = ((const uint4*)WtP16)[idx];
        } else if (idx < 2304) {
            ((uint4*)biasF)[idx - 2048] = ((const uint4*)b_edge)[idx - 2048];
        }
    }

    const int lane = tid & 63;
    const int wave = tid >> 6;
    const int n16 = lane & 15, quad = lane >> 4;
    const int t0 = wave * 32, t1 = t0 + 16;
    const int eH = tid >> 1, halfH = tid & 1;      // gather role

    // B base: row co = cb*16+n16, phys slot = (q&1) ^ ((co>>2)&1); (co>>2)&1 == (n16>>2)&1
    const int qeff = (quad & 1) ^ ((n16 >> 2) & 1);
    const short* Bbase = W16 + n16 * 16 + qeff * 8;          // + cb*256 shorts (imm)
    const float* h0b = hsT + t0 + quad * 4;                  // + c*EPT (imm)
    const float* h1b = hsT + t1 + quad * 4;

    struct PrefT {
        float hv[16];
        float4 e0a, e0b, e1a, e1b;
        int d[8];
    };
    PrefT Pa, Pb;

    auto PREF = [&](int tile, PrefT& P) {
        int base = tile * EPT;
        int s = src[base + eH];
        const float4* hp = (const float4*)(h + (size_t)s * CH + halfH * 16);
        float4 v0 = hp[0], v1 = hp[1], v2 = hp[2], v3 = hp[3];
        *(float4*)&P.hv[0] = v0;  *(float4*)&P.hv[4] = v1;
        *(float4*)&P.hv[8] = v2;  *(float4*)&P.hv[12] = v3;
        if (quad < 2) {
            const float4* p0 = (const float4*)(ea + (size_t)(base + t0 + n16) * FE + quad * 8);
            P.e0a = p0[0]; P.e0b = p0[1];
            const float4* p1 = (const float4*)(ea + (size_t)(base + t1 + n16) * FE + quad * 8);
            P.e1a = p1[0]; P.e1b = p1[1];
        }
#pragma unroll
        for (int r = 0; r < 4; r++) {
            P.d[r]     = dst[base + t0 + quad * 4 + r];
            P.d[4 + r] = dst[base + t1 + quad * 4 + r];
        }
    };

    auto WRITE = [&](PrefT& P) {
        // addr = (halfH*16+j)*128 + eH -> bank eH%32, 2 lanes/bank = free
        float* hd = hsT + halfH * (16 * EPT) + eH;
#pragma unroll
        for (int j = 0; j < 16; j++) hd[j * EPT] = P.hv[j];
    };

    auto COMPUTE = [&](PrefT& P) {
        bf16x8 A0 = (bf16x8){0,0,0,0,0,0,0,0}, A1 = A0;    // quads 2,3: A==0 (k 16..31)
        if (quad < 2) { A0 = cvt8(P.e0a, P.e0b); A1 = cvt8(P.e1a, P.e1b); }

        f32x4 m0[2], m1[2];
        m0[0] = (f32x4){0,0,0,0}; m0[1] = m0[0]; m1[0] = m0[0]; m1[1] = m0[0];

#pragma unroll
        for (int c = 0; c < 32; c++) {
            f32x4 hc0 = *(const f32x4*)(h0b + c * EPT);    // quad-disjoint banks, free
            f32x4 hc1 = *(const f32x4*)(h1b + c * EPT);
            float b0 = biasF[32 * c + n16];                // quad-broadcast, bank-free
            float b1 = biasF[32 * c + 16 + n16];
            f32x4 Cb0 = (f32x4){b0, b0, b0, b0};
            f32x4 Cb1 = (f32x4){b1, b1, b1, b1};
            {
                bf16x8 B = *(const bf16x8*)(Bbase + (2 * c) * 256);
                f32x4 D0 = __builtin_amdgcn_mfma_f32_16x16x32_bf16(A0, B, Cb0, 0, 0, 0);
                f32x4 D1 = __builtin_amdgcn_mfma_f32_16x16x32_bf16(A1, B, Cb0, 0, 0, 0);
                m0[0] += lrelu4(D0) * hc0;
                m1[0] += lrelu4(D1) * hc1;
            }
            {
                bf16x8 B = *(const bf16x8*)(Bbase + (2 * c + 1) * 256);
                f32x4 D0 = __builtin_amdgcn_mfma_f32_16x16x32_bf16(A0, B, Cb1, 0, 0, 0);
                f32x4 D1 = __builtin_amdgcn_mfma_f32_16x16x32_bf16(A1, B, Cb1, 0, 0, 0);
                m0[1] += lrelu4(D0) * hc0;
                m1[1] += lrelu4(D1) * hc1;
            }
        }

        // ---- lean packed-f16 scatter: lane n16 owns (ch n16, ch 16+n16) of row
        // P.d[r] (group t0) / P.d[4+r] (group t1). aggrP layout [node][n16][oh]
        // puts that pair adjacent: one cvt_pkrtz + one pk atomic per (row, r).
        // Lanes of a quad cover n16=0..15 -> 64B contiguous per instruction.
#pragma unroll
        for (int r = 0; r < 4; r++) {
            __half2 v0 = __floats2half2_rn(m0[0][r], m0[1][r]);
            unsafeAtomicAdd((__half2*)(aggrP + (size_t)P.d[r] * CH + n16 * 2), v0);
            __half2 v1 = __floats2half2_rn(m1[0][r], m1[1][r]);
            unsafeAtomicAdd((__half2*)(aggrP + (size_t)P.d[4 + r] * CH + n16 * 2), v1);
        }
    };

    // persistent loop, 2-phase unrolled (static Pa/Pb), STATIC tile stride.
    int T = blockIdx.x;
    PREF(T, Pa);
    while (true) {
        __syncthreads();
        WRITE(Pa);
        __syncthreads();
        int nt = T + PBLK;
        bool more = (nt < NT);
        if (more) PREF(nt, Pb);          // flies under COMPUTE
        COMPUTE(Pa);
        if (!more) break;
        T = nt;

        __syncthreads();
        WRITE(Pb);
        __syncthreads();
        nt = T + PBLK;
        more = (nt < NT);
        if (more) PREF(nt, Pa);
        COMPUTE(Pb);
        if (!more) break;
        T = nt;
    }
}

// ---------------- Kernel 3 (MFMA): out = leaky(aggr + h@W_root + b_conv) @ W_out + b_out
// aggrP is channel-permuted f16: pair (ch n16, ch 16+n16) at [node][n16][0..1].
__global__ void __launch_bounds__(256)
k_node(const __half* __restrict__ aggrP,
       const float* __restrict__ h,
       const float* __restrict__ W_root,
       const float* __restrict__ b_conv,
       const float* __restrict__ W_out,
       const float* __restrict__ b_out,
       float* __restrict__ out) {
    __shared__ short WrB[CH * 40];   // W_root^T bf16: [o][c], stride 40 shorts (80B)
    __shared__ float WoS[CH];
    int tid = threadIdx.x;
    if (tid < 128) {
        int o = tid >> 2, c0 = (tid & 3) * 8;
        short tmp[8] __attribute__((aligned(16)));
#pragma unroll
        for (int j = 0; j < 8; j++) tmp[j] = f2bf(W_root[(c0 + j) * CH + o]);
        *(bf16x8*)&WrB[o * 40 + c0] = *(bf16x8*)tmp;
    } else if (tid < 160) {
        WoS[tid - 128] = W_out[tid - 128];
    }
    __syncthreads();

    int wave = tid >> 6, lane = tid & 63;
    int n16 = lane & 15, quad = lane >> 4;
    int node0 = blockIdx.x * 64 + wave * 16;

    int arow = node0 + n16; if (arow >= NN) arow = NN - 1;
    const float4* hp = (const float4*)(h + (size_t)arow * CH + quad * 8);
    float4 ha = hp[0], hb = hp[1];
    bf16x8 A = cvt8(ha, hb);
    float bc0 = b_conv[n16], bc1 = b_conv[16 + n16];
    f32x4 C0, C1;
#pragma unroll
    for (int r = 0; r < 4; r++) {
        int nr = node0 + quad * 4 + r; int cr = (nr < NN) ? nr : NN - 1;
        __half2 pr = *(const __half2*)(aggrP + (size_t)cr * CH + n16 * 2);
        C0[r] = __half2float(pr.x) + bc0;
        C1[r] = __half2float(pr.y) + bc1;
    }
    bf16x8 B0 = *(const bf16x8*)&WrB[n16 * 40 + quad * 8];
    bf16x8 B1 = *(const bf16x8*)&WrB[(16 + n16) * 40 + quad * 8];
    f32x4 D0 = __builtin_amdgcn_mfma_f32_16x16x32_bf16(A, B0, C0, 0, 0, 0);
    f32x4 D1 = __builtin_amdgcn_mfma_f32_16x16x32_bf16(A, B1, C1, 0, 0, 0);

    float w0 = WoS[n16], w1 = WoS[16 + n16];
    f32x4 p;
#pragma unroll
    for (int r = 0; r < 4; r++)
        p[r] = lrelu(D0[r]) * w0 + lrelu(D1[r]) * w1;
#pragma unroll
    for (int mk = 1; mk < 16; mk <<= 1) {
#pragma unroll
        for (int r = 0; r < 4; r++) p[r] += __shfl_xor(p[r], mk, 64);
    }
    if (n16 == 0) {
        float bo = b_out[0];
#pragma unroll
        for (int r = 0; r < 4; r++) {
            int nr = node0 + quad * 4 + r;
            if (nr < NN) out[nr] = p[r] + bo;
        }
    }
}

extern "C" void kernel_launch(void* const* d_in, const int* in_sizes, int n_in,
                              void* d_out, int out_size, void* d_ws, size_t ws_size,
                              hipStream_t stream) {
    const float* x      = (const float*)d_in[0];
    const int*   ei     = (const int*)d_in[1];
    const float* ea     = (const float*)d_in[2];
    const float* W_in   = (const float*)d_in[3];
    const float* b_in   = (const float*)d_in[4];
    const float* W_edge = (const float*)d_in[5];
    const float* b_edge = (const float*)d_in[6];
    const float* W_root = (const float*)d_in[7];
    const float* b_conv = (const float*)d_in[8];
    const float* W_out  = (const float*)d_in[9];
    const float* b_out  = (const float*)d_in[10];
    float* out   = (float*)d_out;
    float* h     = (float*)d_ws;                      // [NN*CH] f32 (3.2MB)
    __half* aggrP = (__half*)(h + (size_t)NN * CH);   // [NN*CH] f16 permuted (1.6MB)
    short* WtP16 = (short*)(aggrP + (size_t)NN * CH); // [1024*16] bf16 image

    k_pre<<<PROJ_BLOCKS + AUX_BLOCKS, 256, 0, stream>>>(x, W_in, b_in, W_edge, b_edge,
                                                        h, aggrP, WtP16);
    k_edge<<<PBLK, 256, 0, stream>>>(WtP16, ea, ei, ei + EE, h, aggrP, b_edge);
    k_node<<<PROJ_BLOCKS, 256, 0, stream>>>(aggrP, h, W_root, b_conv, W_out, b_out, out);
}